// Round 2
// baseline (117.887 us; speedup 1.0000x reference)
//
#include <hip/hip_runtime.h>
#include <hip/hip_bf16.h>
#include <math.h>

#define NN 2048
#define FF 256
#define HH 64

#define TI 128
#define TJ 64

// ln(0.1/0.9): sigmoid(s) = 0.1 at s = -2.1972245773362196
#define S_BOUND -2.1972245773362196
#define WIN 1e-3f

// ---------------------------------------------------------------------------
// Kernel 1: comb = nf@Wfe.T + bfe + emb;  A = comb@W1a.T;  B = comb@W1b.T + b1
// Emulates numpy-f32/BLAS arithmetic: every output element is a sequential-K
// single-accumulator f32 FMA chain (k ascending), biases added afterward.
// This makes A/B BIT-EXACT to the harness's numpy reference, so the only
// remaining ours-vs-ref noise is the final einsum reduction order.
// ---------------------------------------------------------------------------
__global__ __launch_bounds__(256, 1)
void k1_prep(const float* __restrict__ nf,   // N x F
             const float* __restrict__ emb,  // N x H
             const float* __restrict__ Wfe,  // H x F
             const float* __restrict__ bfe,  // H
             const float* __restrict__ W1,   // H x 2H
             const float* __restrict__ b1,   // H
             float* __restrict__ Af32, float* __restrict__ Bf32)
{
    // 8 rows per block, 256 blocks.
    __shared__ float chunk[64][129];   // +1 pad: lane h reads bank h%32 (2-way = free)
    __shared__ float nf_lds[8][FF];
    __shared__ float comb_lds[8][HH];

    const int t = threadIdx.x;
    const int i0 = blockIdx.x * 8;
    const int h = t & 63;      // output column (lane-distinct)
    const int g = t >> 6;      // wave id -> rows g and g+4 (wave-uniform)

    // stage node_features rows (coalesced)
    for (int k = 0; k < 8; ++k) {
        int e = t + k * 256;
        nf_lds[e >> 8][e & 255] = nf[(size_t)(i0 + (e >> 8)) * FF + (e & 255)];
    }

    float acc0 = 0.0f, acc1 = 0.0f;
    for (int c = 0; c < 2; ++c) {
        __syncthreads();
        // stage Wfe[:, c*128 : (c+1)*128]  (64x128, coalesced)
        for (int k = 0; k < 32; ++k) {
            int e = t + k * 256;
            int r = e >> 7, col = e & 127;
            chunk[r][col] = Wfe[(size_t)r * FF + c * 128 + col];
        }
        __syncthreads();
        const float* w_row = &chunk[h][0];
        const float* nf0 = &nf_lds[g][c * 128];
        const float* nf1 = &nf_lds[g + 4][c * 128];
        // STRICT sequential f ascending, single accumulator, f32 FMA (= sgemm)
        for (int f = 0; f < 128; ++f) {
            float wv = w_row[f];
            acc0 = fmaf(wv, nf0[f], acc0);
            acc1 = fmaf(wv, nf1[f], acc1);
        }
    }
    float bb = bfe[h];
    acc0 = __fadd_rn(__fadd_rn(acc0, bb), emb[(size_t)(i0 + g) * HH + h]);
    acc1 = __fadd_rn(__fadd_rn(acc1, bb), emb[(size_t)(i0 + g + 4) * HH + h]);
    comb_lds[g][h] = acc0;
    comb_lds[g + 4][h] = acc1;
    __syncthreads();

    // stage W1 (64 x 128) reusing chunk
    for (int k = 0; k < 32; ++k) {
        int e = t + k * 256;
        chunk[e >> 7][e & 127] = W1[e];
    }
    __syncthreads();

    float a0 = 0.f, a1 = 0.f, q0 = 0.f, q1 = 0.f;
    // STRICT sequential k ascending, single accumulator per output, f32 FMA
    for (int k = 0; k < HH; ++k) {
        float wa = chunk[h][k];        // W1a[h][k]
        float wb = chunk[h][64 + k];   // W1b[h][k]
        float c0 = comb_lds[g][k];     // wave-uniform broadcast
        float c1 = comb_lds[g + 4][k];
        a0 = fmaf(wa, c0, a0);  a1 = fmaf(wa, c1, a1);
        q0 = fmaf(wb, c0, q0);  q1 = fmaf(wb, c1, q1);
    }
    float b1v = b1[h];
    q0 = __fadd_rn(q0, b1v);
    q1 = __fadd_rn(q1, b1v);

    size_t o0 = (size_t)(i0 + g) * HH + h;
    size_t o1 = (size_t)(i0 + g + 4) * HH + h;
    Af32[o0] = a0;  Af32[o1] = a1;
    Bf32[o0] = q0;  Bf32[o1] = q1;
}

// ---------------------------------------------------------------------------
// Kernel 2: per 128x64 output tile, w[i,j] = sigmoid(sum_h relu(A+B)*W2 + b2),
// masked to upper triangle & w > 0.1. Tiles fully below diagonal zero-fill.
// Near-boundary pairs re-reduced in numpy-einsum's exact SSE order:
// 4 strided lane accumulators (mul+add, NO fma), then (a0+a1)+(a2+a3).
// ---------------------------------------------------------------------------
__global__ __launch_bounds__(256, 2)
void k2_pairs(const float* __restrict__ Af32, const float* __restrict__ Bf32,
              const float* __restrict__ W2, const float* __restrict__ b2,
              float* __restrict__ ew, float* __restrict__ mk)
{
    // Asl row layout (half-split): phys(r) = ((r&4)<<4) + ((r>>3)<<2) + (r&3)
    // -> the 16 lanes' float4 reads are 16B-strided (2-way bank alias = free).
    __shared__ float Asl[64][132];
    __shared__ float Bsl[64][68];
    __shared__ float W2s[64];

    const int t = threadIdx.x;
    const int i0 = blockIdx.y * TI;
    const int j0 = blockIdx.x * TJ;
    const int it = t & 15;   // i sub-block (lane-fast)
    const int jt = t >> 4;   // j sub-block

    // Tile entirely in the lower triangle (i > j for every pair): zero-fill.
    if (i0 > j0) {
        const float4 z = make_float4(0.f, 0.f, 0.f, 0.f);
        #pragma unroll
        for (int e = 0; e < 8; ++e) {
            size_t o = (size_t)(i0 + it * 8 + e) * NN + (j0 + jt * 4);
            *(float4*)(ew + o) = z;
            *(float4*)(mk + o) = z;
        }
        return;
    }

    // --- stage A tile (128 x 64 f32) transposed into Asl[h][phys(r)] ---
    for (int k = 0; k < 8; ++k) {
        int e4 = t + k * 256;
        int r = e4 >> 4, h4 = e4 & 15;
        float4 v = *(const float4*)(Af32 + (size_t)(i0 + r) * HH + h4 * 4);
        int phys = ((r & 4) << 4) + ((r >> 3) << 2) + (r & 3);
        Asl[h4 * 4 + 0][phys] = v.x;
        Asl[h4 * 4 + 1][phys] = v.y;
        Asl[h4 * 4 + 2][phys] = v.z;
        Asl[h4 * 4 + 3][phys] = v.w;
    }
    // --- stage B tile (64 x 64 f32) transposed into Bsl[h][r] ---
    for (int k = 0; k < 4; ++k) {
        int e4 = t + k * 256;
        int r = e4 >> 4, h4 = e4 & 15;
        float4 v = *(const float4*)(Bf32 + (size_t)(j0 + r) * HH + h4 * 4);
        Bsl[h4 * 4 + 0][r] = v.x;
        Bsl[h4 * 4 + 1][r] = v.y;
        Bsl[h4 * 4 + 2][r] = v.z;
        Bsl[h4 * 4 + 3][r] = v.w;
    }
    if (t < 64) W2s[t] = W2[t];
    const float b2f = b2[0];
    __syncthreads();

    float acc[8][4];
    #pragma unroll
    for (int e = 0; e < 8; ++e)
        #pragma unroll
        for (int f = 0; f < 4; ++f) acc[e][f] = 0.0f;

    #pragma unroll 4
    for (int h = 0; h < HH; ++h) {
        const float w2 = W2s[h];
        const float* ar = &Asl[h][0];
        float4 a0 = *(const float4*)(ar + it * 4);        // rows it*8+0..3
        float4 a1 = *(const float4*)(ar + 64 + it * 4);   // rows it*8+4..7
        float4 bv = *(const float4*)(&Bsl[h][jt * 4]);    // cols jt*4+0..3
        float av[8] = {a0.x, a0.y, a0.z, a0.w, a1.x, a1.y, a1.z, a1.w};
        float bb[4] = {bv.x, bv.y, bv.z, bv.w};
        #pragma unroll
        for (int e = 0; e < 8; ++e) {
            #pragma unroll
            for (int f = 0; f < 4; ++f) {
                float tt = av[e] + bb[f];
                tt = fmaxf(tt, 0.0f);
                acc[e][f] = fmaf(tt, w2, acc[e][f]);
            }
        }
    }

    #pragma unroll
    for (int e = 0; e < 8; ++e) {
        const int gi = i0 + it * 8 + e;
        float wv[4], mv[4];
        #pragma unroll
        for (int f = 0; f < 4; ++f) {
            const int gj = j0 + jt * 4 + f;
            float s = acc[e][f] + b2f;
            float w; bool m;
            if (__builtin_expect(gi < gj && fabsf(s - (float)S_BOUND) < WIN, 0)) {
                // Near the mask boundary: redo the h-reduction in numpy
                // einsum's exact f32 order over the bit-exact A/B values.
                const float* Ai = Af32 + (size_t)gi * HH;
                const float* Bj = Bf32 + (size_t)gj * HH;
                float l0 = 0.f, l1 = 0.f, l2 = 0.f, l3 = 0.f;
                for (int hh = 0; hh < HH; hh += 4) {
                    float t0 = fmaxf(__fadd_rn(Ai[hh + 0], Bj[hh + 0]), 0.0f);
                    float t1 = fmaxf(__fadd_rn(Ai[hh + 1], Bj[hh + 1]), 0.0f);
                    float t2 = fmaxf(__fadd_rn(Ai[hh + 2], Bj[hh + 2]), 0.0f);
                    float t3 = fmaxf(__fadd_rn(Ai[hh + 3], Bj[hh + 3]), 0.0f);
                    l0 = __fadd_rn(l0, __fmul_rn(t0, W2s[hh + 0]));
                    l1 = __fadd_rn(l1, __fmul_rn(t1, W2s[hh + 1]));
                    l2 = __fadd_rn(l2, __fmul_rn(t2, W2s[hh + 2]));
                    l3 = __fadd_rn(l3, __fmul_rn(t3, W2s[hh + 3]));
                }
                float sx = __fadd_rn(__fadd_rn(l0, l1), __fadd_rn(l2, l3));
                sx = __fadd_rn(sx, b2f);
                double w64 = 1.0 / (1.0 + exp(-(double)sx));
                w = (float)w64;
                m = w > 0.1f;
            } else {
                w = 1.0f / (1.0f + __expf(-s));
                m = w > 0.1f;
            }
            const bool mm = (gi < gj) && m;
            wv[f] = mm ? w : 0.0f;
            mv[f] = mm ? 1.0f : 0.0f;
        }
        size_t o = (size_t)gi * NN + (j0 + jt * 4);
        *(float4*)(ew + o) = make_float4(wv[0], wv[1], wv[2], wv[3]);
        *(float4*)(mk + o) = make_float4(mv[0], mv[1], mv[2], mv[3]);
    }
}

extern "C" void kernel_launch(void* const* d_in, const int* in_sizes, int n_in,
                              void* d_out, int out_size, void* d_ws, size_t ws_size,
                              hipStream_t stream)
{
    const float* nf  = (const float*)d_in[0];
    const float* emb = (const float*)d_in[1];
    const float* Wfe = (const float*)d_in[2];
    const float* bfe = (const float*)d_in[3];
    const float* W1  = (const float*)d_in[4];
    const float* b1  = (const float*)d_in[5];
    const float* W2  = (const float*)d_in[6];
    const float* b2  = (const float*)d_in[7];

    float* Af32 = (float*)d_ws;                     // N*H floats (512 KB)
    float* Bf32 = Af32 + (size_t)NN * HH;           // N*H floats (512 KB)

    float* ew = (float*)d_out;                      // edge_weights (N*N)
    float* mk = ew + (size_t)NN * NN;               // mask as 0/1 float (N*N)

    k1_prep<<<dim3(NN / 8), dim3(256), 0, stream>>>(
        nf, emb, Wfe, bfe, W1, b1, Af32, Bf32);
    k2_pairs<<<dim3(NN / TJ, NN / TI), dim3(256), 0, stream>>>(
        Af32, Bf32, W2, b2, ew, mk);
}

// Round 4
// 112.870 us; speedup vs baseline: 1.0444x; 1.0444x over previous
//
#include <hip/hip_runtime.h>
#include <hip/hip_bf16.h>
#include <math.h>

#define NN 2048
#define FF 256
#define HH 64

// ln(0.1/0.9): sigmoid(s) = 0.1 at s = -2.1972245773362196
#define S_BOUND -2.1972245773362196
#define WIN 1e-3f

typedef float v2f __attribute__((ext_vector_type(2)));

static __device__ __forceinline__ v2f add2(v2f a, v2f b) {
    v2f r; r.x = __fadd_rn(a.x, b.x); r.y = __fadd_rn(a.y, b.y); return r;
}
static __device__ __forceinline__ v2f max2z(v2f a) {
    v2f r; r.x = fmaxf(a.x, 0.0f); r.y = fmaxf(a.y, 0.0f); return r;
}
static __device__ __forceinline__ v2f fma2(v2f a, v2f b, v2f c) {
    v2f r; r.x = fmaf(a.x, b.x, c.x); r.y = fmaf(a.y, b.y, c.y); return r;
}

// ---------------------------------------------------------------------------
// Kernel 1: comb = nf@Wfe.T + bfe + emb;  A = comb@W1a.T;  B = comb@W1b.T + b1
// Emulates numpy-f32/BLAS arithmetic: every output element is a sequential-K
// single-accumulator f32 FMA chain (k ascending), biases added afterward.
// DO NOT change the reduction order — it is bit-matched to the np reference.
// ---------------------------------------------------------------------------
__global__ __launch_bounds__(256, 1)
void k1_prep(const float* __restrict__ nf,   // N x F
             const float* __restrict__ emb,  // N x H
             const float* __restrict__ Wfe,  // H x F
             const float* __restrict__ bfe,  // H
             const float* __restrict__ W1,   // H x 2H
             const float* __restrict__ b1,   // H
             float* __restrict__ Af32, float* __restrict__ Bf32)
{
    __shared__ float chunk[64][129];   // +1 pad
    __shared__ float nf_lds[8][FF];
    __shared__ float comb_lds[8][HH];

    const int t = threadIdx.x;
    const int i0 = blockIdx.x * 8;
    const int h = t & 63;      // output column (lane-distinct)
    const int g = t >> 6;      // wave id -> rows g and g+4 (wave-uniform)

    // stage node_features rows (float4, coalesced): 8x256 floats
    #pragma unroll
    for (int k = 0; k < 2; ++k) {
        int e4 = t + k * 256;
        int r = e4 >> 6, c4 = e4 & 63;
        float4 v = *(const float4*)(nf + (size_t)(i0 + r) * FF + c4 * 4);
        nf_lds[r][c4 * 4 + 0] = v.x;
        nf_lds[r][c4 * 4 + 1] = v.y;
        nf_lds[r][c4 * 4 + 2] = v.z;
        nf_lds[r][c4 * 4 + 3] = v.w;
    }

    float acc0 = 0.0f, acc1 = 0.0f;
    for (int c = 0; c < 2; ++c) {
        __syncthreads();
        // stage Wfe[:, c*128:(c+1)*128] (64x128 floats, float4 coalesced)
        #pragma unroll
        for (int k = 0; k < 8; ++k) {
            int e4 = t + k * 256;
            int r = e4 >> 5, c4 = e4 & 31;
            float4 v = *(const float4*)(Wfe + (size_t)r * FF + c * 128 + c4 * 4);
            chunk[r][c4 * 4 + 0] = v.x;
            chunk[r][c4 * 4 + 1] = v.y;
            chunk[r][c4 * 4 + 2] = v.z;
            chunk[r][c4 * 4 + 3] = v.w;
        }
        __syncthreads();
        const float* w_row = &chunk[h][0];
        const float* nf0 = &nf_lds[g][c * 128];
        const float* nf1 = &nf_lds[g + 4][c * 128];
        // STRICT sequential f ascending, single accumulator, f32 FMA (= sgemm)
        #pragma unroll 16
        for (int f = 0; f < 128; ++f) {
            float wv = w_row[f];
            acc0 = fmaf(wv, nf0[f], acc0);
            acc1 = fmaf(wv, nf1[f], acc1);
        }
    }
    float bb = bfe[h];
    acc0 = __fadd_rn(__fadd_rn(acc0, bb), emb[(size_t)(i0 + g) * HH + h]);
    acc1 = __fadd_rn(__fadd_rn(acc1, bb), emb[(size_t)(i0 + g + 4) * HH + h]);
    comb_lds[g][h] = acc0;
    comb_lds[g + 4][h] = acc1;
    __syncthreads();

    // stage W1 (64 x 128 floats, flat float4)
    #pragma unroll
    for (int k = 0; k < 8; ++k) {
        int e4 = t + k * 256;
        float4 v = *(const float4*)(W1 + (size_t)e4 * 4);
        int r = e4 >> 5, c4 = e4 & 31;
        chunk[r][c4 * 4 + 0] = v.x;
        chunk[r][c4 * 4 + 1] = v.y;
        chunk[r][c4 * 4 + 2] = v.z;
        chunk[r][c4 * 4 + 3] = v.w;
    }
    __syncthreads();

    float a0 = 0.f, a1 = 0.f, q0 = 0.f, q1 = 0.f;
    // STRICT sequential k ascending, single accumulator per output, f32 FMA
    #pragma unroll 8
    for (int k = 0; k < HH; ++k) {
        float wa = chunk[h][k];        // W1a[h][k]
        float wb = chunk[h][64 + k];   // W1b[h][k]
        float c0 = comb_lds[g][k];     // wave-uniform broadcast
        float c1 = comb_lds[g + 4][k];
        a0 = fmaf(wa, c0, a0);  a1 = fmaf(wa, c1, a1);
        q0 = fmaf(wb, c0, q0);  q1 = fmaf(wb, c1, q1);
    }
    float b1v = b1[h];
    q0 = __fadd_rn(q0, b1v);
    q1 = __fadd_rn(q1, b1v);

    size_t o0 = (size_t)(i0 + g) * HH + h;
    size_t o1 = (size_t)(i0 + g + 4) * HH + h;
    Af32[o0] = a0;  Af32[o1] = a1;
    Bf32[o0] = q0;  Bf32[o1] = q1;
}

// ---------------------------------------------------------------------------
// Kernel 2: 64x64 output tiles; w[i,j] = sigmoid(sum_h relu(A_ih+B_jh)W2_h+b2),
// masked to upper triangle & w > 0.1. Strictly-lower tiles zero-fill.
// Per-output accumulation: ascending h, single accumulator, f32 fma —
// identical numerics to the verified round-2 kernel (packed across outputs
// only). Near-boundary pairs re-reduced in numpy-einsum's exact SSE order.
// ---------------------------------------------------------------------------
__global__ __launch_bounds__(256, 4)
void k2_pairs(const float* __restrict__ Af32, const float* __restrict__ Bf32,
              const float* __restrict__ W2, const float* __restrict__ b2,
              float* __restrict__ ew, float* __restrict__ mk)
{
    __shared__ float Asl[64][68];   // [h][i], 17408 B
    __shared__ float Bsl[64][68];   // [h][j], 17408 B
    __shared__ float W2s[64];

    const int t = threadIdx.x;
    const int i0 = blockIdx.y * 64;
    const int j0 = blockIdx.x * 64;
    const int it = t & 15;   // i quad (lane-fast)
    const int jt = t >> 4;   // j quad

    // Strictly-lower tile (i > j for every pair): zero-fill and exit.
    if (i0 > j0) {
        const float4 z = make_float4(0.f, 0.f, 0.f, 0.f);
        #pragma unroll
        for (int e = 0; e < 4; ++e) {
            size_t o = (size_t)(i0 + it * 4 + e) * NN + (j0 + jt * 4);
            *(float4*)(ew + o) = z;
            *(float4*)(mk + o) = z;
        }
        return;
    }

    // --- stage A tile (64 x 64 f32) transposed into Asl[h][i] ---
    #pragma unroll
    for (int k = 0; k < 4; ++k) {
        int e4 = t + k * 256;
        int r = e4 >> 4, h4 = e4 & 15;
        float4 v = *(const float4*)(Af32 + (size_t)(i0 + r) * HH + h4 * 4);
        Asl[h4 * 4 + 0][r] = v.x;
        Asl[h4 * 4 + 1][r] = v.y;
        Asl[h4 * 4 + 2][r] = v.z;
        Asl[h4 * 4 + 3][r] = v.w;
    }
    // --- stage B tile (64 x 64 f32) transposed into Bsl[h][j] ---
    #pragma unroll
    for (int k = 0; k < 4; ++k) {
        int e4 = t + k * 256;
        int r = e4 >> 4, h4 = e4 & 15;
        float4 v = *(const float4*)(Bf32 + (size_t)(j0 + r) * HH + h4 * 4);
        Bsl[h4 * 4 + 0][r] = v.x;
        Bsl[h4 * 4 + 1][r] = v.y;
        Bsl[h4 * 4 + 2][r] = v.z;
        Bsl[h4 * 4 + 3][r] = v.w;
    }
    if (t < 64) W2s[t] = W2[t];
    const float b2f = b2[0];
    __syncthreads();

    v2f acc[4][2];
    #pragma unroll
    for (int e = 0; e < 4; ++e) {
        acc[e][0] = (v2f)0.0f;
        acc[e][1] = (v2f)0.0f;
    }

    #pragma unroll 4
    for (int h = 0; h < HH; ++h) {
        const float w2 = W2s[h];
        v2f w22; w22.x = w2; w22.y = w2;
        float4 av = *(const float4*)(&Asl[h][it * 4]);
        float4 bv = *(const float4*)(&Bsl[h][jt * 4]);
        v2f b01; b01.x = bv.x; b01.y = bv.y;
        v2f b23; b23.x = bv.z; b23.y = bv.w;
        float ae[4] = {av.x, av.y, av.z, av.w};
        #pragma unroll
        for (int e = 0; e < 4; ++e) {
            v2f aa; aa.x = ae[e]; aa.y = ae[e];
            acc[e][0] = fma2(max2z(add2(aa, b01)), w22, acc[e][0]);
            acc[e][1] = fma2(max2z(add2(aa, b23)), w22, acc[e][1]);
        }
    }

    #pragma unroll
    for (int e = 0; e < 4; ++e) {
        const int gi = i0 + it * 4 + e;
        float sv[4] = {acc[e][0].x, acc[e][0].y, acc[e][1].x, acc[e][1].y};
        float wv[4], mv[4];
        #pragma unroll
        for (int f = 0; f < 4; ++f) {
            const int gj = j0 + jt * 4 + f;
            float s = sv[f] + b2f;
            float w; bool m;
            if (__builtin_expect(gi < gj && fabsf(s - (float)S_BOUND) < WIN, 0)) {
                // Near the mask boundary: redo the h-reduction in numpy
                // einsum's exact f32 order over the bit-exact A/B values.
                const float* Ai = Af32 + (size_t)gi * HH;
                const float* Bj = Bf32 + (size_t)gj * HH;
                float l0 = 0.f, l1 = 0.f, l2 = 0.f, l3 = 0.f;
                for (int hh = 0; hh < HH; hh += 4) {
                    float t0 = fmaxf(__fadd_rn(Ai[hh + 0], Bj[hh + 0]), 0.0f);
                    float t1 = fmaxf(__fadd_rn(Ai[hh + 1], Bj[hh + 1]), 0.0f);
                    float t2 = fmaxf(__fadd_rn(Ai[hh + 2], Bj[hh + 2]), 0.0f);
                    float t3 = fmaxf(__fadd_rn(Ai[hh + 3], Bj[hh + 3]), 0.0f);
                    l0 = __fadd_rn(l0, __fmul_rn(t0, W2s[hh + 0]));
                    l1 = __fadd_rn(l1, __fmul_rn(t1, W2s[hh + 1]));
                    l2 = __fadd_rn(l2, __fmul_rn(t2, W2s[hh + 2]));
                    l3 = __fadd_rn(l3, __fmul_rn(t3, W2s[hh + 3]));
                }
                float sx = __fadd_rn(__fadd_rn(l0, l1), __fadd_rn(l2, l3));
                sx = __fadd_rn(sx, b2f);
                double w64 = 1.0 / (1.0 + exp(-(double)sx));
                w = (float)w64;
                m = w > 0.1f;
            } else {
                w = 1.0f / (1.0f + __expf(-s));
                m = w > 0.1f;
            }
            const bool mm = (gi < gj) && m;
            wv[f] = mm ? w : 0.0f;
            mv[f] = mm ? 1.0f : 0.0f;
        }
        size_t o = (size_t)gi * NN + (j0 + jt * 4);
        *(float4*)(ew + o) = make_float4(wv[0], wv[1], wv[2], wv[3]);
        *(float4*)(mk + o) = make_float4(mv[0], mv[1], mv[2], mv[3]);
    }
}

extern "C" void kernel_launch(void* const* d_in, const int* in_sizes, int n_in,
                              void* d_out, int out_size, void* d_ws, size_t ws_size,
                              hipStream_t stream)
{
    const float* nf  = (const float*)d_in[0];
    const float* emb = (const float*)d_in[1];
    const float* Wfe = (const float*)d_in[2];
    const float* bfe = (const float*)d_in[3];
    const float* W1  = (const float*)d_in[4];
    const float* b1  = (const float*)d_in[5];
    const float* W2  = (const float*)d_in[6];
    const float* b2  = (const float*)d_in[7];

    float* Af32 = (float*)d_ws;                     // N*H floats (512 KB)
    float* Bf32 = Af32 + (size_t)NN * HH;           // N*H floats (512 KB)

    float* ew = (float*)d_out;                      // edge_weights (N*N)
    float* mk = ew + (size_t)NN * NN;               // mask as 0/1 float (N*N)

    k1_prep<<<dim3(NN / 8), dim3(256), 0, stream>>>(
        nf, emb, Wfe, bfe, W1, b1, Af32, Bf32);
    k2_pairs<<<dim3(NN / 64, NN / 64), dim3(256), 0, stream>>>(
        Af32, Bf32, W2, b2, ew, mk);
}

// Round 6
// 106.713 us; speedup vs baseline: 1.1047x; 1.0577x over previous
//
#include <hip/hip_runtime.h>
#include <hip/hip_bf16.h>
#include <math.h>

#define NN 2048
#define FF 256
#define HH 64

// ln(0.1/0.9): sigmoid(s) = 0.1 at s = -2.1972245773362196
#define S_BOUND -2.1972245773362196
#define WIN 1e-3f

#define NT 32            // 32x32 tiles of 64x64
#define N_UPPER 528      // NT*(NT+1)/2  (compute tiles, by<=bx)
#define N_LOWER 496      // NT*(NT-1)/2  (strict-lower zero tiles)

typedef float v2f __attribute__((ext_vector_type(2)));

static __device__ __forceinline__ v2f add2(v2f a, v2f b) {
    v2f r; r.x = __fadd_rn(a.x, b.x); r.y = __fadd_rn(a.y, b.y); return r;
}
static __device__ __forceinline__ v2f max2z(v2f a) {
    v2f r; r.x = fmaxf(a.x, 0.0f); r.y = fmaxf(a.y, 0.0f); return r;
}
static __device__ __forceinline__ v2f fma2(v2f a, v2f b, v2f c) {
    v2f r; r.x = fmaf(a.x, b.x, c.x); r.y = fmaf(a.y, b.y, c.y); return r;
}

// ---------------------------------------------------------------------------
// Kernel 1: comb = nf@Wfe.T + bfe + emb;  A = comb@W1a.T;  B = comb@W1b.T + b1
// Emulates numpy-f32/BLAS arithmetic: every output element is a sequential-K
// single-accumulator f32 FMA chain (k ascending), biases added afterward.
// DO NOT change the reduction order — it is bit-matched to the np reference.
// ---------------------------------------------------------------------------
__global__ __launch_bounds__(256, 1)
void k1_prep(const float* __restrict__ nf,   // N x F
             const float* __restrict__ emb,  // N x H
             const float* __restrict__ Wfe,  // H x F
             const float* __restrict__ bfe,  // H
             const float* __restrict__ W1,   // H x 2H
             const float* __restrict__ b1,   // H
             float* __restrict__ Af32, float* __restrict__ Bf32)
{
    __shared__ float chunk[64][129];   // +1 pad
    __shared__ float nf_lds[8][FF];
    __shared__ float comb_lds[8][HH];

    const int t = threadIdx.x;
    const int i0 = blockIdx.x * 8;
    const int h = t & 63;      // output column (lane-distinct)
    const int g = t >> 6;      // wave id -> rows g and g+4 (wave-uniform)

    // stage node_features rows (float4, coalesced): 8x256 floats
    #pragma unroll
    for (int k = 0; k < 2; ++k) {
        int e4 = t + k * 256;
        int r = e4 >> 6, c4 = e4 & 63;
        float4 v = *(const float4*)(nf + (size_t)(i0 + r) * FF + c4 * 4);
        nf_lds[r][c4 * 4 + 0] = v.x;
        nf_lds[r][c4 * 4 + 1] = v.y;
        nf_lds[r][c4 * 4 + 2] = v.z;
        nf_lds[r][c4 * 4 + 3] = v.w;
    }

    float acc0 = 0.0f, acc1 = 0.0f;
    for (int c = 0; c < 2; ++c) {
        __syncthreads();
        // stage Wfe[:, c*128:(c+1)*128] (64x128 floats, float4 coalesced)
        #pragma unroll
        for (int k = 0; k < 8; ++k) {
            int e4 = t + k * 256;
            int r = e4 >> 5, c4 = e4 & 31;
            float4 v = *(const float4*)(Wfe + (size_t)r * FF + c * 128 + c4 * 4);
            chunk[r][c4 * 4 + 0] = v.x;
            chunk[r][c4 * 4 + 1] = v.y;
            chunk[r][c4 * 4 + 2] = v.z;
            chunk[r][c4 * 4 + 3] = v.w;
        }
        __syncthreads();
        const float* w_row = &chunk[h][0];
        const float* nf0 = &nf_lds[g][c * 128];
        const float* nf1 = &nf_lds[g + 4][c * 128];
        // STRICT sequential f ascending, single accumulator, f32 FMA (= sgemm)
        #pragma unroll 16
        for (int f = 0; f < 128; ++f) {
            float wv = w_row[f];
            acc0 = fmaf(wv, nf0[f], acc0);
            acc1 = fmaf(wv, nf1[f], acc1);
        }
    }
    float bb = bfe[h];
    acc0 = __fadd_rn(__fadd_rn(acc0, bb), emb[(size_t)(i0 + g) * HH + h]);
    acc1 = __fadd_rn(__fadd_rn(acc1, bb), emb[(size_t)(i0 + g + 4) * HH + h]);
    comb_lds[g][h] = acc0;
    comb_lds[g + 4][h] = acc1;
    __syncthreads();

    // stage W1 (64 x 128 floats, flat float4)
    #pragma unroll
    for (int k = 0; k < 8; ++k) {
        int e4 = t + k * 256;
        float4 v = *(const float4*)(W1 + (size_t)e4 * 4);
        int r = e4 >> 5, c4 = e4 & 31;
        chunk[r][c4 * 4 + 0] = v.x;
        chunk[r][c4 * 4 + 1] = v.y;
        chunk[r][c4 * 4 + 2] = v.z;
        chunk[r][c4 * 4 + 3] = v.w;
    }
    __syncthreads();

    float a0 = 0.f, a1 = 0.f, q0 = 0.f, q1 = 0.f;
    // STRICT sequential k ascending, single accumulator per output, f32 FMA
    #pragma unroll 8
    for (int k = 0; k < HH; ++k) {
        float wa = chunk[h][k];        // W1a[h][k]
        float wb = chunk[h][64 + k];   // W1b[h][k]
        float c0 = comb_lds[g][k];     // wave-uniform broadcast
        float c1 = comb_lds[g + 4][k];
        a0 = fmaf(wa, c0, a0);  a1 = fmaf(wa, c1, a1);
        q0 = fmaf(wb, c0, q0);  q1 = fmaf(wb, c1, q1);
    }
    float b1v = b1[h];
    q0 = __fadd_rn(q0, b1v);
    q1 = __fadd_rn(q1, b1v);

    size_t o0 = (size_t)(i0 + g) * HH + h;
    size_t o1 = (size_t)(i0 + g + 4) * HH + h;
    Af32[o0] = a0;  Af32[o1] = a1;
    Bf32[o0] = q0;  Bf32[o1] = q1;
}

// ---------------------------------------------------------------------------
// Kernel 2: 1-D grid, triangular decode. Blocks [0,528) = upper-triangle
// compute tiles (by<=bx) in row-major triangle order; blocks [528,1024) =
// strict-lower zero tiles. Thread map: it=t>>4 (i-quad), jt=t&15 (j-quad)
// -> per-wave stores are 4 rows x 256B contiguous.
// Per-output accumulation: ascending h, single accumulator, f32 fma —
// bit-identical to the verified round-2/4 chain. Near-boundary pairs
// re-reduced in numpy-einsum's exact SSE order.
// ---------------------------------------------------------------------------
__global__ __launch_bounds__(256, 4)
void k2_pairs(const float* __restrict__ Af32, const float* __restrict__ Bf32,
              const float* __restrict__ W2, const float* __restrict__ b2,
              float* __restrict__ ew, float* __restrict__ mk)
{
    __shared__ float Asl[64][68];   // [h][i], 17408 B
    __shared__ float Bsl[64][68];   // [h][j], 17408 B
    __shared__ float W2s[64];

    const int t = threadIdx.x;
    const int b = blockIdx.x;
    const int it = t >> 4;   // i quad (4 distinct per wave)
    const int jt = t & 15;   // j quad (16 distinct per wave -> 256B row spans)

    if (b >= N_UPPER) {
        // strict-lower zero tile: decode z -> (by, bx), by in [1,31], bx < by
        int z = b - N_UPPER;
        int by = (int)((1.0f + sqrtf((float)(1 + 8 * z))) * 0.5f);
        while (by * (by - 1) / 2 > z) --by;
        while ((by + 1) * by / 2 <= z) ++by;
        int bx = z - by * (by - 1) / 2;
        const int i0 = by * 64, j0 = bx * 64;
        const float4 zf = make_float4(0.f, 0.f, 0.f, 0.f);
        #pragma unroll
        for (int e = 0; e < 4; ++e) {
            size_t o = (size_t)(i0 + it * 4 + e) * NN + (j0 + jt * 4);
            *(float4*)(ew + o) = zf;
            *(float4*)(mk + o) = zf;
        }
        return;
    }

    // upper tile: decode b -> (by, bx), by<=bx; row by starts at by*(65-by)/2
    int by = (int)((65.0f - sqrtf((float)(4225 - 8 * b))) * 0.5f);
    while (by * (65 - by) / 2 > b) --by;
    while ((by + 1) * (64 - by) / 2 <= b) ++by;
    int bx = by + (b - by * (65 - by) / 2);
    const int i0 = by * 64, j0 = bx * 64;

    // --- stage A tile (64 x 64 f32) transposed into Asl[h][i] ---
    #pragma unroll
    for (int k = 0; k < 4; ++k) {
        int e4 = t + k * 256;
        int r = e4 >> 4, h4 = e4 & 15;
        float4 v = *(const float4*)(Af32 + (size_t)(i0 + r) * HH + h4 * 4);
        Asl[h4 * 4 + 0][r] = v.x;
        Asl[h4 * 4 + 1][r] = v.y;
        Asl[h4 * 4 + 2][r] = v.z;
        Asl[h4 * 4 + 3][r] = v.w;
    }
    // --- stage B tile (64 x 64 f32) transposed into Bsl[h][j] ---
    #pragma unroll
    for (int k = 0; k < 4; ++k) {
        int e4 = t + k * 256;
        int r = e4 >> 4, h4 = e4 & 15;
        float4 v = *(const float4*)(Bf32 + (size_t)(j0 + r) * HH + h4 * 4);
        Bsl[h4 * 4 + 0][r] = v.x;
        Bsl[h4 * 4 + 1][r] = v.y;
        Bsl[h4 * 4 + 2][r] = v.z;
        Bsl[h4 * 4 + 3][r] = v.w;
    }
    if (t < 64) W2s[t] = W2[t];
    const float b2f = b2[0];
    __syncthreads();

    v2f acc[4][2];
    #pragma unroll
    for (int e = 0; e < 4; ++e) {
        acc[e][0] = (v2f)0.0f;
        acc[e][1] = (v2f)0.0f;
    }

    #pragma unroll 4
    for (int h = 0; h < HH; ++h) {
        const float w2 = W2s[h];
        v2f w22; w22.x = w2; w22.y = w2;
        float4 av = *(const float4*)(&Asl[h][it * 4]);   // 4 i-values
        float4 bv = *(const float4*)(&Bsl[h][jt * 4]);   // 4 j-values
        v2f b01; b01.x = bv.x; b01.y = bv.y;
        v2f b23; b23.x = bv.z; b23.y = bv.w;
        float ae[4] = {av.x, av.y, av.z, av.w};
        #pragma unroll
        for (int e = 0; e < 4; ++e) {
            v2f aa; aa.x = ae[e]; aa.y = ae[e];
            acc[e][0] = fma2(max2z(add2(aa, b01)), w22, acc[e][0]);
            acc[e][1] = fma2(max2z(add2(aa, b23)), w22, acc[e][1]);
        }
    }

    #pragma unroll
    for (int e = 0; e < 4; ++e) {
        const int gi = i0 + it * 4 + e;
        float sv[4] = {acc[e][0].x, acc[e][0].y, acc[e][1].x, acc[e][1].y};
        float wv[4], mv[4];
        #pragma unroll
        for (int f = 0; f < 4; ++f) {
            const int gj = j0 + jt * 4 + f;
            float s = sv[f] + b2f;
            float w; bool m;
            if (__builtin_expect(gi < gj && fabsf(s - (float)S_BOUND) < WIN, 0)) {
                // Near the mask boundary: redo the h-reduction in numpy
                // einsum's exact f32 order over the bit-exact A/B values.
                const float* Ai = Af32 + (size_t)gi * HH;
                const float* Bj = Bf32 + (size_t)gj * HH;
                float l0 = 0.f, l1 = 0.f, l2 = 0.f, l3 = 0.f;
                for (int hh = 0; hh < HH; hh += 4) {
                    float t0 = fmaxf(__fadd_rn(Ai[hh + 0], Bj[hh + 0]), 0.0f);
                    float t1 = fmaxf(__fadd_rn(Ai[hh + 1], Bj[hh + 1]), 0.0f);
                    float t2 = fmaxf(__fadd_rn(Ai[hh + 2], Bj[hh + 2]), 0.0f);
                    float t3 = fmaxf(__fadd_rn(Ai[hh + 3], Bj[hh + 3]), 0.0f);
                    l0 = __fadd_rn(l0, __fmul_rn(t0, W2s[hh + 0]));
                    l1 = __fadd_rn(l1, __fmul_rn(t1, W2s[hh + 1]));
                    l2 = __fadd_rn(l2, __fmul_rn(t2, W2s[hh + 2]));
                    l3 = __fadd_rn(l3, __fmul_rn(t3, W2s[hh + 3]));
                }
                float sx = __fadd_rn(__fadd_rn(l0, l1), __fadd_rn(l2, l3));
                sx = __fadd_rn(sx, b2f);
                double w64 = 1.0 / (1.0 + exp(-(double)sx));
                w = (float)w64;
                m = w > 0.1f;
            } else {
                w = 1.0f / (1.0f + __expf(-s));
                m = w > 0.1f;
            }
            const bool mm = (gi < gj) && m;
            wv[f] = mm ? w : 0.0f;
            mv[f] = mm ? 1.0f : 0.0f;
        }
        size_t o = (size_t)gi * NN + (j0 + jt * 4);
        *(float4*)(ew + o) = make_float4(wv[0], wv[1], wv[2], wv[3]);
        *(float4*)(mk + o) = make_float4(mv[0], mv[1], mv[2], mv[3]);
    }
}

extern "C" void kernel_launch(void* const* d_in, const int* in_sizes, int n_in,
                              void* d_out, int out_size, void* d_ws, size_t ws_size,
                              hipStream_t stream)
{
    const float* nf  = (const float*)d_in[0];
    const float* emb = (const float*)d_in[1];
    const float* Wfe = (const float*)d_in[2];
    const float* bfe = (const float*)d_in[3];
    const float* W1  = (const float*)d_in[4];
    const float* b1  = (const float*)d_in[5];
    const float* W2  = (const float*)d_in[6];
    const float* b2  = (const float*)d_in[7];

    float* Af32 = (float*)d_ws;                     // N*H floats (512 KB)
    float* Bf32 = Af32 + (size_t)NN * HH;           // N*H floats (512 KB)

    float* ew = (float*)d_out;                      // edge_weights (N*N)
    float* mk = ew + (size_t)NN * NN;               // mask as 0/1 float (N*N)

    k1_prep<<<dim3(NN / 8), dim3(256), 0, stream>>>(
        nf, emb, Wfe, bfe, W1, b1, Af32, Bf32);
    k2_pairs<<<dim3(N_UPPER + N_LOWER), dim3(256), 0, stream>>>(
        Af32, Bf32, W2, b2, ew, mk);
}

// Round 7
// 106.488 us; speedup vs baseline: 1.1071x; 1.0021x over previous
//
#include <hip/hip_runtime.h>
#include <hip/hip_bf16.h>
#include <math.h>

#define NN 2048
#define FF 256
#define HH 64

// ln(0.1/0.9): sigmoid(s) = 0.1 at s = -2.1972245773362196
#define S_BOUND -2.1972245773362196
#define WIN 1e-3f

#define NT 32            // 32x32 tiles of 64x64
#define N_UPPER 528      // NT*(NT+1)/2  (compute tiles, by<=bx)
#define N_LOWER 496      // NT*(NT-1)/2  (strict-lower zero tiles)

typedef float v2f __attribute__((ext_vector_type(2)));

static __device__ __forceinline__ v2f add2(v2f a, v2f b) {
    v2f r; r.x = __fadd_rn(a.x, b.x); r.y = __fadd_rn(a.y, b.y); return r;
}
static __device__ __forceinline__ v2f max2z(v2f a) {
    v2f r; r.x = fmaxf(a.x, 0.0f); r.y = fmaxf(a.y, 0.0f); return r;
}
static __device__ __forceinline__ v2f fma2(v2f a, v2f b, v2f c) {
    v2f r; r.x = fmaf(a.x, b.x, c.x); r.y = fmaf(a.y, b.y, c.y); return r;
}

// ---------------------------------------------------------------------------
// Kernel 1: comb = nf@Wfe.T + bfe + emb;  A = comb@W1a.T;  B = comb@W1b.T + b1
// Emulates numpy-f32/BLAS arithmetic: every output element is a sequential-K
// single-accumulator f32 FMA chain (k ascending), biases added afterward.
// DO NOT change the reduction order — it is bit-matched to the np reference.
// ---------------------------------------------------------------------------
__global__ __launch_bounds__(256, 1)
void k1_prep(const float* __restrict__ nf,   // N x F
             const float* __restrict__ emb,  // N x H
             const float* __restrict__ Wfe,  // H x F
             const float* __restrict__ bfe,  // H
             const float* __restrict__ W1,   // H x 2H
             const float* __restrict__ b1,   // H
             float* __restrict__ Af32, float* __restrict__ Bf32)
{
    __shared__ float chunk[64][129];   // +1 pad
    __shared__ float nf_lds[8][FF];
    __shared__ float comb_lds[8][HH];

    const int t = threadIdx.x;
    const int i0 = blockIdx.x * 8;
    const int h = t & 63;      // output column (lane-distinct)
    const int g = t >> 6;      // wave id -> rows g and g+4 (wave-uniform)

    // stage node_features rows (float4, coalesced): 8x256 floats
    #pragma unroll
    for (int k = 0; k < 2; ++k) {
        int e4 = t + k * 256;
        int r = e4 >> 6, c4 = e4 & 63;
        float4 v = *(const float4*)(nf + (size_t)(i0 + r) * FF + c4 * 4);
        nf_lds[r][c4 * 4 + 0] = v.x;
        nf_lds[r][c4 * 4 + 1] = v.y;
        nf_lds[r][c4 * 4 + 2] = v.z;
        nf_lds[r][c4 * 4 + 3] = v.w;
    }

    float acc0 = 0.0f, acc1 = 0.0f;
    for (int c = 0; c < 2; ++c) {
        __syncthreads();
        // stage Wfe[:, c*128:(c+1)*128] (64x128 floats, float4 coalesced)
        #pragma unroll
        for (int k = 0; k < 8; ++k) {
            int e4 = t + k * 256;
            int r = e4 >> 5, c4 = e4 & 31;
            float4 v = *(const float4*)(Wfe + (size_t)r * FF + c * 128 + c4 * 4);
            chunk[r][c4 * 4 + 0] = v.x;
            chunk[r][c4 * 4 + 1] = v.y;
            chunk[r][c4 * 4 + 2] = v.z;
            chunk[r][c4 * 4 + 3] = v.w;
        }
        __syncthreads();
        const float* w_row = &chunk[h][0];
        const float* nf0 = &nf_lds[g][c * 128];
        const float* nf1 = &nf_lds[g + 4][c * 128];
        // STRICT sequential f ascending, single accumulator, f32 FMA (= sgemm)
        #pragma unroll 16
        for (int f = 0; f < 128; ++f) {
            float wv = w_row[f];
            acc0 = fmaf(wv, nf0[f], acc0);
            acc1 = fmaf(wv, nf1[f], acc1);
        }
    }
    float bb = bfe[h];
    acc0 = __fadd_rn(__fadd_rn(acc0, bb), emb[(size_t)(i0 + g) * HH + h]);
    acc1 = __fadd_rn(__fadd_rn(acc1, bb), emb[(size_t)(i0 + g + 4) * HH + h]);
    comb_lds[g][h] = acc0;
    comb_lds[g + 4][h] = acc1;
    __syncthreads();

    // stage W1 (64 x 128 floats, flat float4)
    #pragma unroll
    for (int k = 0; k < 8; ++k) {
        int e4 = t + k * 256;
        float4 v = *(const float4*)(W1 + (size_t)e4 * 4);
        int r = e4 >> 5, c4 = e4 & 31;
        chunk[r][c4 * 4 + 0] = v.x;
        chunk[r][c4 * 4 + 1] = v.y;
        chunk[r][c4 * 4 + 2] = v.z;
        chunk[r][c4 * 4 + 3] = v.w;
    }
    __syncthreads();

    float a0 = 0.f, a1 = 0.f, q0 = 0.f, q1 = 0.f;
    // STRICT sequential k ascending, single accumulator per output, f32 FMA
    #pragma unroll 8
    for (int k = 0; k < HH; ++k) {
        float wa = chunk[h][k];        // W1a[h][k]
        float wb = chunk[h][64 + k];   // W1b[h][k]
        float c0 = comb_lds[g][k];     // wave-uniform broadcast
        float c1 = comb_lds[g + 4][k];
        a0 = fmaf(wa, c0, a0);  a1 = fmaf(wa, c1, a1);
        q0 = fmaf(wb, c0, q0);  q1 = fmaf(wb, c1, q1);
    }
    float b1v = b1[h];
    q0 = __fadd_rn(q0, b1v);
    q1 = __fadd_rn(q1, b1v);

    size_t o0 = (size_t)(i0 + g) * HH + h;
    size_t o1 = (size_t)(i0 + g + 4) * HH + h;
    Af32[o0] = a0;  Af32[o1] = a1;
    Bf32[o0] = q0;  Bf32[o1] = q1;
}

// ---------------------------------------------------------------------------
// Boundary recompute: numpy-einsum's exact f32 SSE order (4 strided lane
// accumulators, mul+add no-fma, tree combine), then fp64 sigmoid.
// noinline: rare path (~1e-4 of pairs), keep out of the hot loop's icache.
// ---------------------------------------------------------------------------
__device__ __attribute__((noinline))
float boundary_w(const float* __restrict__ Ai, const float* __restrict__ Bj,
                 const float* __restrict__ W2, float b2f)
{
    float l0 = 0.f, l1 = 0.f, l2 = 0.f, l3 = 0.f;
    for (int hh = 0; hh < HH; hh += 4) {
        float t0 = fmaxf(__fadd_rn(Ai[hh + 0], Bj[hh + 0]), 0.0f);
        float t1 = fmaxf(__fadd_rn(Ai[hh + 1], Bj[hh + 1]), 0.0f);
        float t2 = fmaxf(__fadd_rn(Ai[hh + 2], Bj[hh + 2]), 0.0f);
        float t3 = fmaxf(__fadd_rn(Ai[hh + 3], Bj[hh + 3]), 0.0f);
        l0 = __fadd_rn(l0, __fmul_rn(t0, W2[hh + 0]));
        l1 = __fadd_rn(l1, __fmul_rn(t1, W2[hh + 1]));
        l2 = __fadd_rn(l2, __fmul_rn(t2, W2[hh + 2]));
        l3 = __fadd_rn(l3, __fmul_rn(t3, W2[hh + 3]));
    }
    float sx = __fadd_rn(__fadd_rn(l0, l1), __fadd_rn(l2, l3));
    sx = __fadd_rn(sx, b2f);
    double w64 = 1.0 / (1.0 + exp(-(double)sx));
    return (float)w64;
}

// ---------------------------------------------------------------------------
// Kernel 2: 528 blocks. Block b:
//   (1) if b < 496: zero-fill strict-lower tile b (stores issued FIRST,
//       fire-and-forget — they drain underneath staging+compute);
//   (2) compute upper-triangle tile b (by<=bx), identical numerics to the
//       verified round-6 chain.
// Thread map: it=t>>4 (i-quad), jt=t&15 (j-quad) -> per-quarter-wave stores
// are 256B contiguous.
// ---------------------------------------------------------------------------
__global__ __launch_bounds__(256, 4)
void k2_pairs(const float* __restrict__ Af32, const float* __restrict__ Bf32,
              const float* __restrict__ W2, const float* __restrict__ b2,
              float* __restrict__ ew, float* __restrict__ mk)
{
    __shared__ float Asl[64][68];   // [h][i], 17408 B
    __shared__ float Bsl[64][68];   // [h][j], 17408 B
    __shared__ float W2s[64];

    const int t = threadIdx.x;
    const int b = blockIdx.x;
    const int it = t >> 4;   // i quad
    const int jt = t & 15;   // j quad (16 distinct per wave -> 256B row spans)

    // --- fused zero-fill of one strict-lower tile (blocks 0..495) ---
    if (b < N_LOWER) {
        int z = b;
        int zby = (int)((1.0f + sqrtf((float)(1 + 8 * z))) * 0.5f);
        while (zby * (zby - 1) / 2 > z) --zby;
        while ((zby + 1) * zby / 2 <= z) ++zby;
        int zbx = z - zby * (zby - 1) / 2;
        const int zi0 = zby * 64, zj0 = zbx * 64;
        const float4 zf = make_float4(0.f, 0.f, 0.f, 0.f);
        #pragma unroll
        for (int e = 0; e < 4; ++e) {
            size_t o = (size_t)(zi0 + it * 4 + e) * NN + (zj0 + jt * 4);
            *(float4*)(ew + o) = zf;
            *(float4*)(mk + o) = zf;
        }
    }

    // --- compute-tile decode: b -> (by, bx), by<=bx; row by starts at by*(65-by)/2
    int by = (int)((65.0f - sqrtf((float)(4225 - 8 * b))) * 0.5f);
    while (by * (65 - by) / 2 > b) --by;
    while ((by + 1) * (64 - by) / 2 <= b) ++by;
    int bx = by + (b - by * (65 - by) / 2);
    const int i0 = by * 64, j0 = bx * 64;

    // --- stage A tile (64 x 64 f32) transposed into Asl[h][i] ---
    #pragma unroll
    for (int k = 0; k < 4; ++k) {
        int e4 = t + k * 256;
        int r = e4 >> 4, h4 = e4 & 15;
        float4 v = *(const float4*)(Af32 + (size_t)(i0 + r) * HH + h4 * 4);
        Asl[h4 * 4 + 0][r] = v.x;
        Asl[h4 * 4 + 1][r] = v.y;
        Asl[h4 * 4 + 2][r] = v.z;
        Asl[h4 * 4 + 3][r] = v.w;
    }
    // --- stage B tile (64 x 64 f32) transposed into Bsl[h][j] ---
    #pragma unroll
    for (int k = 0; k < 4; ++k) {
        int e4 = t + k * 256;
        int r = e4 >> 4, h4 = e4 & 15;
        float4 v = *(const float4*)(Bf32 + (size_t)(j0 + r) * HH + h4 * 4);
        Bsl[h4 * 4 + 0][r] = v.x;
        Bsl[h4 * 4 + 1][r] = v.y;
        Bsl[h4 * 4 + 2][r] = v.z;
        Bsl[h4 * 4 + 3][r] = v.w;
    }
    if (t < 64) W2s[t] = W2[t];
    const float b2f = b2[0];
    __syncthreads();

    v2f acc[4][2];
    #pragma unroll
    for (int e = 0; e < 4; ++e) {
        acc[e][0] = (v2f)0.0f;
        acc[e][1] = (v2f)0.0f;
    }

    #pragma unroll 4
    for (int h = 0; h < HH; ++h) {
        const float w2 = W2s[h];
        v2f w22; w22.x = w2; w22.y = w2;
        float4 av = *(const float4*)(&Asl[h][it * 4]);   // 4 i-values
        float4 bv = *(const float4*)(&Bsl[h][jt * 4]);   // 4 j-values
        v2f b01; b01.x = bv.x; b01.y = bv.y;
        v2f b23; b23.x = bv.z; b23.y = bv.w;
        float ae[4] = {av.x, av.y, av.z, av.w};
        #pragma unroll
        for (int e = 0; e < 4; ++e) {
            v2f aa; aa.x = ae[e]; aa.y = ae[e];
            acc[e][0] = fma2(max2z(add2(aa, b01)), w22, acc[e][0]);
            acc[e][1] = fma2(max2z(add2(aa, b23)), w22, acc[e][1]);
        }
    }

    #pragma unroll
    for (int e = 0; e < 4; ++e) {
        const int gi = i0 + it * 4 + e;
        float sv[4] = {acc[e][0].x, acc[e][0].y, acc[e][1].x, acc[e][1].y};
        float wv[4], mv[4];
        #pragma unroll
        for (int f = 0; f < 4; ++f) {
            const int gj = j0 + jt * 4 + f;
            float s = sv[f] + b2f;
            float w; bool m;
            if (__builtin_expect(gi < gj && fabsf(s - (float)S_BOUND) < WIN, 0)) {
                w = boundary_w(Af32 + (size_t)gi * HH, Bf32 + (size_t)gj * HH,
                               W2, b2f);
                m = w > 0.1f;
            } else {
                w = 1.0f / (1.0f + __expf(-s));
                m = w > 0.1f;
            }
            const bool mm = (gi < gj) && m;
            wv[f] = mm ? w : 0.0f;
            mv[f] = mm ? 1.0f : 0.0f;
        }
        size_t o = (size_t)gi * NN + (j0 + jt * 4);
        *(float4*)(ew + o) = make_float4(wv[0], wv[1], wv[2], wv[3]);
        *(float4*)(mk + o) = make_float4(mv[0], mv[1], mv[2], mv[3]);
    }
}

extern "C" void kernel_launch(void* const* d_in, const int* in_sizes, int n_in,
                              void* d_out, int out_size, void* d_ws, size_t ws_size,
                              hipStream_t stream)
{
    const float* nf  = (const float*)d_in[0];
    const float* emb = (const float*)d_in[1];
    const float* Wfe = (const float*)d_in[2];
    const float* bfe = (const float*)d_in[3];
    const float* W1  = (const float*)d_in[4];
    const float* b1  = (const float*)d_in[5];
    const float* W2  = (const float*)d_in[6];
    const float* b2  = (const float*)d_in[7];

    float* Af32 = (float*)d_ws;                     // N*H floats (512 KB)
    float* Bf32 = Af32 + (size_t)NN * HH;           // N*H floats (512 KB)

    float* ew = (float*)d_out;                      // edge_weights (N*N)
    float* mk = ew + (size_t)NN * NN;               // mask as 0/1 float (N*N)

    k1_prep<<<dim3(NN / 8), dim3(256), 0, stream>>>(
        nf, emb, Wfe, bfe, W1, b1, Af32, Bf32);
    k2_pairs<<<dim3(N_UPPER), dim3(256), 0, stream>>>(
        Af32, Bf32, W2, b2, ew, mk);
}